// Round 3
// baseline (79.967 us; speedup 1.0000x reference)
//
#include <hip/hip_runtime.h>

#define N_CLASSES 512
#define EPS_F 1e-7f
#define BLOCK 512

// One fused kernel, 1 sample/thread (max TLP — the gather is latency-bound):
// per-sample NLL -> per-block LDS class histogram -> global atomic flush ->
// last block (ticket) computes mean of per-class means, writes the scalar.
__global__ __launch_bounds__(BLOCK) void nll_fused_kernel(
    const float* __restrict__ close_er,
    const int*   __restrict__ y,
    const float* __restrict__ max_dis,
    const float* __restrict__ margin_p,
    float* __restrict__ g_sums,
    float* __restrict__ g_counts,
    int*   __restrict__ g_ticket,
    float* __restrict__ out,
    int n)
{
    __shared__ float        s_md[N_CLASSES];
    __shared__ float        s_sum[N_CLASSES];
    __shared__ unsigned int s_cnt[N_CLASSES];
    __shared__ float        s_red[16];
    __shared__ bool         s_last;

    const int tid = threadIdx.x;
    const float margin = margin_p[0];

    for (int c = tid; c < N_CLASSES; c += BLOCK) {
        s_md[c]  = max_dis[c];
        s_sum[c] = 0.0f;
        s_cnt[c] = 0u;
    }
    __syncthreads();

    // ---- phase 1: gather + NLL + LDS histogram (1 sample/thread) ----
    const int i = blockIdx.x * BLOCK + tid;
    if (i < n) {
        const int c = y[i];
        const float ce = close_er[(size_t)i * N_CLASSES + c];
        const float x  = ce - s_md[c] - margin;
        float s = 1.0f / (1.0f + __expf(-x));
        s = fminf(fmaxf(s, EPS_F), 1.0f - EPS_F);
        atomicAdd(&s_sum[c], -__logf(s));
        atomicAdd(&s_cnt[c], 1u);
    }
    __syncthreads();

    // ---- phase 2: flush per-block partials to global (1 class/thread) ----
    {
        const int c = tid;  // BLOCK == N_CLASSES
        const unsigned int cnt = s_cnt[c];
        if (cnt != 0u) {
            atomicAdd(&g_sums[c],   s_sum[c]);
            atomicAdd(&g_counts[c], (float)cnt);  // exact: counts < 2^24
        }
    }

    // ---- phase 3: last block finalizes ----
    __threadfence();
    if (tid == 0) {
        const int t = atomicAdd(g_ticket, 1);
        s_last = (t == (int)gridDim.x - 1);
    }
    __syncthreads();
    if (!s_last) return;
    __threadfence();  // acquire: observe all blocks' flushes

    float m = 0.0f, j = 0.0f;
    {
        const int c = tid;
        const float cnt = g_counts[c];
        if (cnt > 0.0f) {
            m = g_sums[c] / cnt;
            j = 1.0f;
        }
    }
    // wave reduce (64 lanes), then across the 8 waves via LDS
    for (int off = 32; off > 0; off >>= 1) {
        m += __shfl_down(m, off);
        j += __shfl_down(j, off);
    }
    const int wave = tid >> 6;
    if ((tid & 63) == 0) {
        s_red[wave * 2]     = m;
        s_red[wave * 2 + 1] = j;
    }
    __syncthreads();
    if (tid == 0) {
        float M = 0.0f, J = 0.0f;
        for (int w = 0; w < BLOCK / 64; ++w) {
            M += s_red[w * 2];
            J += s_red[w * 2 + 1];
        }
        out[0] = M / J;
    }
}

extern "C" void kernel_launch(void* const* d_in, const int* in_sizes, int n_in,
                              void* d_out, int out_size, void* d_ws, size_t ws_size,
                              hipStream_t stream) {
    const float* close_er = (const float*)d_in[0];
    const int*   y        = (const int*)d_in[1];
    const float* max_dis  = (const float*)d_in[2];
    const float* margin   = (const float*)d_in[3];
    float* out = (float*)d_out;

    const int n = in_sizes[1];  // N samples

    float* g_sums   = (float*)d_ws;
    float* g_counts = g_sums + N_CLASSES;
    int*   g_ticket = (int*)(g_counts + N_CLASSES);

    // ws is poisoned once (0xAA) and never re-poisoned between replays:
    // zero accumulators + ticket every call (deterministic).
    hipMemsetAsync(d_ws, 0, (2 * N_CLASSES + 1) * sizeof(float), stream);

    const int grid = (n + BLOCK - 1) / BLOCK;  // 512 blocks at N=262144
    nll_fused_kernel<<<grid, BLOCK, 0, stream>>>(close_er, y, max_dis, margin,
                                                 g_sums, g_counts, g_ticket,
                                                 out, n);
}

// Round 4
// 22.736 us; speedup vs baseline: 3.5172x; 3.5172x over previous
//
#include <hip/hip_runtime.h>

#define N_CLASSES 512
#define EPS_F 1e-7f
#define BLOCK 1024

// ---------------- Path A (atomic-free, 2 nodes) ----------------

// K1: gather + NLL + per-block LDS class histogram; flush = coalesced plain
// stores to per-block partial slots (no atomics, no zero-init needed: every
// slot is written unconditionally, including zero-count classes).
__global__ __launch_bounds__(BLOCK) void nll_part_kernel(
    const float* __restrict__ close_er,
    const int*   __restrict__ y,
    const float* __restrict__ max_dis,
    const float* __restrict__ margin_p,
    float*          __restrict__ p_sums,   // [grid][512] f32
    unsigned short* __restrict__ p_cnts,   // [grid][512] u16 (<=1024 fits)
    int n)
{
    __shared__ float        s_md[N_CLASSES];
    __shared__ float        s_sum[N_CLASSES];
    __shared__ unsigned int s_cnt[N_CLASSES];

    const int tid = threadIdx.x;
    const float margin = margin_p[0];

    if (tid < N_CLASSES) {
        s_md[tid]  = max_dis[tid];
        s_sum[tid] = 0.0f;
        s_cnt[tid] = 0u;
    }
    __syncthreads();

    const int i = blockIdx.x * BLOCK + tid;
    if (i < n) {
        const int c = y[i];
        const float ce = close_er[(size_t)i * N_CLASSES + c];
        const float x  = ce - s_md[c] - margin;
        float s = 1.0f / (1.0f + __expf(-x));
        s = fminf(fmaxf(s, EPS_F), 1.0f - EPS_F);
        atomicAdd(&s_sum[c], -__logf(s));
        atomicAdd(&s_cnt[c], 1u);
    }
    __syncthreads();

    if (tid < N_CLASSES) {
        const size_t o = (size_t)blockIdx.x * N_CLASSES + tid;
        p_sums[o] = s_sum[tid];                       // coalesced 2KB
        p_cnts[o] = (unsigned short)s_cnt[tid];       // coalesced 1KB
    }
}

// K2: one block, 1024 threads. Thread t accumulates class (t&511) over rows
// b = (t>>9) + 2*i  -> global index t + 1024*i : perfectly coalesced loads,
// register-only accumulation, then LDS merge + block reduce -> scalar.
__global__ __launch_bounds__(1024) void finalize_part_kernel(
    const float*          __restrict__ p_sums,
    const unsigned short* __restrict__ p_cnts,
    float* __restrict__ out,
    int R)  // number of partial rows (= K1 grid)
{
    __shared__ float        s1[1024];
    __shared__ unsigned int c1[1024];
    __shared__ float        s_red[32];

    const int t  = threadIdx.x;
    const int c  = t & (N_CLASSES - 1);
    const int b0 = t >> 9;

    float        sum = 0.0f;
    unsigned int cnt = 0u;
    #pragma unroll 4
    for (int b = b0; b < R; b += 2) {
        sum += p_sums[(size_t)b * N_CLASSES + c];
        cnt += p_cnts[(size_t)b * N_CLASSES + c];
    }
    s1[t] = sum;
    c1[t] = cnt;
    __syncthreads();

    float m = 0.0f, j = 0.0f;
    if (t < N_CLASSES) {
        const float        S = s1[t] + s1[t + 512];
        const unsigned int C = c1[t] + c1[t + 512];
        if (C > 0u) { m = S / (float)C; j = 1.0f; }
    }
    for (int off = 32; off > 0; off >>= 1) {
        m += __shfl_down(m, off);
        j += __shfl_down(j, off);
    }
    if ((t & 63) == 0) {
        s_red[(t >> 6) * 2]     = m;
        s_red[(t >> 6) * 2 + 1] = j;
    }
    __syncthreads();
    if (t == 0) {
        float M = 0.0f, J = 0.0f;
        for (int w = 0; w < 16; ++w) {
            M += s_red[w * 2];
            J += s_red[w * 2 + 1];
        }
        out[0] = M / J;
    }
}

// ---------------- Path B (fallback: R1's proven 3-node atomic path) --------

__global__ __launch_bounds__(BLOCK) void nll_hist_kernel(
    const float* __restrict__ close_er,
    const int*   __restrict__ y,
    const float* __restrict__ max_dis,
    const float* __restrict__ margin_p,
    float* __restrict__ g_sums,
    float* __restrict__ g_counts,
    int n)
{
    __shared__ float        s_md[N_CLASSES];
    __shared__ float        s_sum[N_CLASSES];
    __shared__ unsigned int s_cnt[N_CLASSES];

    const int tid = threadIdx.x;
    const float margin = margin_p[0];

    if (tid < N_CLASSES) {
        s_md[tid]  = max_dis[tid];
        s_sum[tid] = 0.0f;
        s_cnt[tid] = 0u;
    }
    __syncthreads();

    const int i = blockIdx.x * BLOCK + tid;
    if (i < n) {
        const int c = y[i];
        const float ce = close_er[(size_t)i * N_CLASSES + c];
        const float x  = ce - s_md[c] - margin;
        float s = 1.0f / (1.0f + __expf(-x));
        s = fminf(fmaxf(s, EPS_F), 1.0f - EPS_F);
        atomicAdd(&s_sum[c], -__logf(s));
        atomicAdd(&s_cnt[c], 1u);
    }
    __syncthreads();

    if (tid < N_CLASSES) {
        const unsigned int cnt = s_cnt[tid];
        if (cnt != 0u) {
            atomicAdd(&g_sums[tid],   s_sum[tid]);
            atomicAdd(&g_counts[tid], (float)cnt);
        }
    }
}

__global__ __launch_bounds__(512) void finalize_kernel(
    const float* __restrict__ g_sums,
    const float* __restrict__ g_counts,
    float* __restrict__ out)
{
    __shared__ float s_red[16];
    const int t = threadIdx.x;
    float m = 0.0f, j = 0.0f;
    const float cnt = g_counts[t];
    if (cnt > 0.0f) { m = g_sums[t] / cnt; j = 1.0f; }
    for (int off = 32; off > 0; off >>= 1) {
        m += __shfl_down(m, off);
        j += __shfl_down(j, off);
    }
    if ((t & 63) == 0) {
        s_red[(t >> 6) * 2]     = m;
        s_red[(t >> 6) * 2 + 1] = j;
    }
    __syncthreads();
    if (t == 0) {
        float M = 0.0f, J = 0.0f;
        for (int w = 0; w < 8; ++w) {
            M += s_red[w * 2];
            J += s_red[w * 2 + 1];
        }
        out[0] = M / J;
    }
}

// ---------------------------------------------------------------------------

extern "C" void kernel_launch(void* const* d_in, const int* in_sizes, int n_in,
                              void* d_out, int out_size, void* d_ws, size_t ws_size,
                              hipStream_t stream) {
    const float* close_er = (const float*)d_in[0];
    const int*   y        = (const int*)d_in[1];
    const float* max_dis  = (const float*)d_in[2];
    const float* margin   = (const float*)d_in[3];
    float* out = (float*)d_out;

    const int n    = in_sizes[1];                 // N samples
    const int grid = (n + BLOCK - 1) / BLOCK;     // 256 at N=262144

    const size_t needA = (size_t)grid * N_CLASSES * (sizeof(float) + sizeof(unsigned short));

    if (ws_size >= needA) {
        // Path A: 2 nodes, no atomics, no memset.
        float*          p_sums = (float*)d_ws;
        unsigned short* p_cnts = (unsigned short*)(p_sums + (size_t)grid * N_CLASSES);
        nll_part_kernel<<<grid, BLOCK, 0, stream>>>(close_er, y, max_dis, margin,
                                                    p_sums, p_cnts, n);
        finalize_part_kernel<<<1, 1024, 0, stream>>>(p_sums, p_cnts, out, grid);
    } else {
        // Path B: proven 3-node atomic path (R1).
        float* g_sums   = (float*)d_ws;
        float* g_counts = g_sums + N_CLASSES;
        hipMemsetAsync(d_ws, 0, 2 * N_CLASSES * sizeof(float), stream);
        nll_hist_kernel<<<grid, BLOCK, 0, stream>>>(close_er, y, max_dis, margin,
                                                    g_sums, g_counts, n);
        finalize_kernel<<<1, N_CLASSES, 0, stream>>>(g_sums, g_counts, out);
    }
}

// Round 5
// 19.108 us; speedup vs baseline: 4.1850x; 1.1899x over previous
//
#include <hip/hip_runtime.h>

#define N_CLASSES 512
#define EPS_F 1e-7f
#define BLOCK 1024
#define RB 16  // rows per K2a block

// ---------------- Path A (atomic-free, 3 nodes, no memset) ----------------

// K1: gather + NLL + per-block LDS class histogram; flush = coalesced plain
// stores of per-block partials (every slot written -> no zero-init needed).
__global__ __launch_bounds__(BLOCK) void nll_part_kernel(
    const float* __restrict__ close_er,
    const int*   __restrict__ y,
    const float* __restrict__ max_dis,
    const float* __restrict__ margin_p,
    float*          __restrict__ p_sums,   // [R][512] f32
    unsigned short* __restrict__ p_cnts,   // [R][512] u16 (block count <= 1024)
    int n)
{
    __shared__ float        s_md[N_CLASSES];
    __shared__ float        s_sum[N_CLASSES];
    __shared__ unsigned int s_cnt[N_CLASSES];

    const int tid = threadIdx.x;
    const float margin = margin_p[0];

    if (tid < N_CLASSES) {
        s_md[tid]  = max_dis[tid];
        s_sum[tid] = 0.0f;
        s_cnt[tid] = 0u;
    }
    __syncthreads();

    const int i = blockIdx.x * BLOCK + tid;
    if (i < n) {
        const int c = y[i];
        // use-once line: nontemporal (no L1/L2 allocation)
        const float ce = __builtin_nontemporal_load(&close_er[(size_t)i * N_CLASSES + c]);
        const float x  = ce - s_md[c] - margin;
        float s = 1.0f / (1.0f + __expf(-x));
        s = fminf(fmaxf(s, EPS_F), 1.0f - EPS_F);
        atomicAdd(&s_sum[c], -__logf(s));
        atomicAdd(&s_cnt[c], 1u);
    }
    __syncthreads();

    if (tid < N_CLASSES) {
        const size_t o = (size_t)blockIdx.x * N_CLASSES + tid;
        p_sums[o] = s_sum[tid];                   // coalesced 2 KB
        p_cnts[o] = (unsigned short)s_cnt[tid];   // coalesced 1 KB
    }
}

// K2a: tree stage. Block b reduces rows [b*RB, b*RB+RB) of the partial
// matrix; thread t owns class t&511, row-phase t>>9 -> fully coalesced.
__global__ __launch_bounds__(1024) void reduce_part_kernel(
    const float*          __restrict__ p_sums,
    const unsigned short* __restrict__ p_cnts,
    float* __restrict__ q_sums,   // [nb][512] f32
    float* __restrict__ q_cnts,   // [nb][512] f32 (exact: < 2^24)
    int R)
{
    __shared__ float s1[1024];
    __shared__ float c1[1024];

    const int t = threadIdx.x;
    const int c = t & (N_CLASSES - 1);
    const int g = t >> 9;
    const int r0 = blockIdx.x * RB;

    float        sum = 0.0f;
    unsigned int cnt = 0u;
    #pragma unroll
    for (int k = g; k < RB; k += 2) {
        const int r = r0 + k;
        if (r < R) {
            sum += p_sums[(size_t)r * N_CLASSES + c];
            cnt += p_cnts[(size_t)r * N_CLASSES + c];
        }
    }
    s1[t] = sum;
    c1[t] = (float)cnt;
    __syncthreads();

    if (t < N_CLASSES) {
        const size_t o = (size_t)blockIdx.x * N_CLASSES + t;
        q_sums[o] = s1[t] + s1[t + 512];
        q_cnts[o] = c1[t] + c1[t + 512];
    }
}

// K3: final. One block combines nb q-rows, per-class mean, mean over
// non-empty classes -> scalar.
__global__ __launch_bounds__(1024) void finalize_part_kernel(
    const float* __restrict__ q_sums,
    const float* __restrict__ q_cnts,
    float* __restrict__ out,
    int nb)
{
    __shared__ float s1[1024];
    __shared__ float c1[1024];
    __shared__ float s_red[32];

    const int t = threadIdx.x;
    const int c = t & (N_CLASSES - 1);
    const int g = t >> 9;

    float sum = 0.0f, cnt = 0.0f;
    for (int r = g; r < nb; r += 2) {
        sum += q_sums[(size_t)r * N_CLASSES + c];
        cnt += q_cnts[(size_t)r * N_CLASSES + c];
    }
    s1[t] = sum;
    c1[t] = cnt;
    __syncthreads();

    float m = 0.0f, j = 0.0f;
    if (t < N_CLASSES) {
        const float S = s1[t] + s1[t + 512];
        const float C = c1[t] + c1[t + 512];
        if (C > 0.0f) { m = S / C; j = 1.0f; }
    }
    for (int off = 32; off > 0; off >>= 1) {
        m += __shfl_down(m, off);
        j += __shfl_down(j, off);
    }
    if ((t & 63) == 0) {
        s_red[(t >> 6) * 2]     = m;
        s_red[(t >> 6) * 2 + 1] = j;
    }
    __syncthreads();
    if (t == 0) {
        float M = 0.0f, J = 0.0f;
        for (int w = 0; w < 16; ++w) {
            M += s_red[w * 2];
            J += s_red[w * 2 + 1];
        }
        out[0] = M / J;
    }
}

// ---------------- Path B (fallback: R1's proven 3-node atomic path) --------

__global__ __launch_bounds__(BLOCK) void nll_hist_kernel(
    const float* __restrict__ close_er,
    const int*   __restrict__ y,
    const float* __restrict__ max_dis,
    const float* __restrict__ margin_p,
    float* __restrict__ g_sums,
    float* __restrict__ g_counts,
    int n)
{
    __shared__ float        s_md[N_CLASSES];
    __shared__ float        s_sum[N_CLASSES];
    __shared__ unsigned int s_cnt[N_CLASSES];

    const int tid = threadIdx.x;
    const float margin = margin_p[0];

    if (tid < N_CLASSES) {
        s_md[tid]  = max_dis[tid];
        s_sum[tid] = 0.0f;
        s_cnt[tid] = 0u;
    }
    __syncthreads();

    const int i = blockIdx.x * BLOCK + tid;
    if (i < n) {
        const int c = y[i];
        const float ce = __builtin_nontemporal_load(&close_er[(size_t)i * N_CLASSES + c]);
        const float x  = ce - s_md[c] - margin;
        float s = 1.0f / (1.0f + __expf(-x));
        s = fminf(fmaxf(s, EPS_F), 1.0f - EPS_F);
        atomicAdd(&s_sum[c], -__logf(s));
        atomicAdd(&s_cnt[c], 1u);
    }
    __syncthreads();

    if (tid < N_CLASSES) {
        const unsigned int cnt = s_cnt[tid];
        if (cnt != 0u) {
            atomicAdd(&g_sums[tid],   s_sum[tid]);
            atomicAdd(&g_counts[tid], (float)cnt);
        }
    }
}

__global__ __launch_bounds__(512) void finalize_kernel(
    const float* __restrict__ g_sums,
    const float* __restrict__ g_counts,
    float* __restrict__ out)
{
    __shared__ float s_red[16];
    const int t = threadIdx.x;
    float m = 0.0f, j = 0.0f;
    const float cnt = g_counts[t];
    if (cnt > 0.0f) { m = g_sums[t] / cnt; j = 1.0f; }
    for (int off = 32; off > 0; off >>= 1) {
        m += __shfl_down(m, off);
        j += __shfl_down(j, off);
    }
    if ((t & 63) == 0) {
        s_red[(t >> 6) * 2]     = m;
        s_red[(t >> 6) * 2 + 1] = j;
    }
    __syncthreads();
    if (t == 0) {
        float M = 0.0f, J = 0.0f;
        for (int w = 0; w < 8; ++w) {
            M += s_red[w * 2];
            J += s_red[w * 2 + 1];
        }
        out[0] = M / J;
    }
}

// ---------------------------------------------------------------------------

extern "C" void kernel_launch(void* const* d_in, const int* in_sizes, int n_in,
                              void* d_out, int out_size, void* d_ws, size_t ws_size,
                              hipStream_t stream) {
    const float* close_er = (const float*)d_in[0];
    const int*   y        = (const int*)d_in[1];
    const float* max_dis  = (const float*)d_in[2];
    const float* margin   = (const float*)d_in[3];
    float* out = (float*)d_out;

    const int n    = in_sizes[1];               // N samples
    const int R    = (n + BLOCK - 1) / BLOCK;   // 256 partial rows
    const int nb   = (R + RB - 1) / RB;         // 16 tree blocks

    const size_t pA_bytes = (size_t)R * N_CLASSES * (sizeof(float) + sizeof(unsigned short));
    const size_t qA_bytes = (size_t)nb * N_CLASSES * 2 * sizeof(float);

    if (ws_size >= pA_bytes + qA_bytes) {
        // Path A: 3 nodes, no atomics, no memset.
        float*          p_sums = (float*)d_ws;
        unsigned short* p_cnts = (unsigned short*)(p_sums + (size_t)R * N_CLASSES);
        float*          q_sums = (float*)((char*)d_ws + (size_t)R * N_CLASSES * 6);
        float*          q_cnts = q_sums + (size_t)nb * N_CLASSES;

        nll_part_kernel<<<R, BLOCK, 0, stream>>>(close_er, y, max_dis, margin,
                                                 p_sums, p_cnts, n);
        reduce_part_kernel<<<nb, 1024, 0, stream>>>(p_sums, p_cnts, q_sums, q_cnts, R);
        finalize_part_kernel<<<1, 1024, 0, stream>>>(q_sums, q_cnts, out, nb);
    } else {
        // Path B: proven 3-node atomic path (R1).
        float* g_sums   = (float*)d_ws;
        float* g_counts = g_sums + N_CLASSES;
        hipMemsetAsync(d_ws, 0, 2 * N_CLASSES * sizeof(float), stream);
        nll_hist_kernel<<<R, BLOCK, 0, stream>>>(close_er, y, max_dis, margin,
                                                 g_sums, g_counts, n);
        finalize_kernel<<<1, N_CLASSES, 0, stream>>>(g_sums, g_counts, out);
    }
}